// Round 3
// baseline (2014.479 us; speedup 1.0000x reference)
//
#include <hip/hip_runtime.h>

typedef float f32x4 __attribute__((ext_vector_type(4)));

#define TN 2048
// LDS byte offsets (dynamic LDS; base from pointer cast)
#define W1B 0u        // [129][256] f32 (row 128 = zeros)      132096 B
#define W2B 132096u   // [65][16][4] f32 (group 64 = zeros)     16640 B
#define XB  148736u   // [2064] f32 (i <-> x[i-3], zero pad)     8256 B
// total 156992 B

// ---------------- prep: repack weights into d_ws ----------------
__global__ __launch_bounds__(256)
void prep_kernel(const float* __restrict__ w1, const float* __restrict__ w2,
                 float* __restrict__ w1T, float* __restrict__ w2Q) {
    int bid = blockIdx.x;
    if (bid < 32) {
        __shared__ float tile[32][33];
        int h0 = (bid >> 2) << 5, c0 = (bid & 3) << 5;
        int tx = threadIdx.x & 31, ty = threadIdx.x >> 5;
        #pragma unroll
        for (int i = ty; i < 32; i += 8) tile[i][tx] = w1[(h0 + i) * 128 + (c0 + tx)];
        __syncthreads();
        #pragma unroll
        for (int i = ty; i < 32; i += 8) w1T[(c0 + i) * 256 + (h0 + tx)] = tile[tx][i];
    } else {
        for (int idx = threadIdx.x; idx < 65 * 64; idx += 256) {
            int l = idx >> 6, n = (idx >> 2) & 15, j = idx & 3;
            w2Q[idx] = (l < 64 && n < 10) ? w2[n * 256 + 4 * l + j] : 0.0f;
        }
    }
}

__device__ __forceinline__ void ds_load4(f32x4& d, unsigned addr) {
    asm volatile("ds_read_b128 %0, %1" : "=v"(d) : "v"(addr));
}
#define WAIT_LGKM(N) do { asm volatile("s_waitcnt lgkmcnt(" #N ")" ::: "memory"); \
                          __builtin_amdgcn_sched_barrier(0); } while (0)

// uniform (SGPR) ascending-index pop from 128-bit mask; pad = 128 (zero row)
__device__ __forceinline__ int pop_next(unsigned long long& lo, unsigned long long& hi) {
    bool hl = lo != 0ull, hh = hi != 0ull, have = hl || hh;
    unsigned long long sel  = hl ? lo : hi;
    unsigned long long selg = have ? sel : 1ull;
    int c = __builtin_ctzll(selg) + (hl ? 0 : 64);
    c = have ? c : 128;
    unsigned long long cl = selg & (selg - 1ull);
    lo = hl ? cl : lo;
    hi = (hl || !hh) ? hi : cl;
    return c;
}
// pop from single 64-bit mask; pad = 64 (zero group)
__device__ __forceinline__ int pop_one(unsigned long long& m) {
    bool have = m != 0ull;
    unsigned long long g = have ? m : 1ull;
    int l = have ? __builtin_ctzll(g) : 64;
    m = g & (g - 1ull);
    return l;
}

__device__ __forceinline__ void issue_l2(unsigned long long ma, unsigned long long mb,
                                         unsigned w1a, f32x4 (&dst)[8],
                                         unsigned long long& olo, unsigned long long& ohi) {
    unsigned long long lo = ma, hi = mb;
    #pragma unroll
    for (int i = 0; i < 8; ++i) {
        int c = pop_next(lo, hi);
        ds_load4(dst[i], w1a + ((unsigned)c << 10));
    }
    olo = lo; ohi = hi;
}

__device__ __forceinline__ void if1_step(const float (&xw)[12], int off,
                                         const float (&cwa)[7], const float (&cwb)[7],
                                         float& v1a, float& v1b,
                                         unsigned long long& ma, unsigned long long& mb) {
    float xca = 0.f, xcb = 0.f;
    #pragma unroll
    for (int k = 0; k < 7; ++k) {
        float xv = xw[off + k];
        xca = fmaf(xv, cwa[k], xca);
        xcb = fmaf(xv, cwb[k], xcb);
    }
    float na = v1a + xca, nb = v1b + xcb;
    bool sa = na >= 1.0f, sb = nb >= 1.0f;
    ma = __ballot(sa); mb = __ballot(sb);
    v1a = sa ? 0.f : na; v1b = sb ? 0.f : nb;
}

// deferred L3 consume: order (l0,j0..3),(l1,...),(l2,...),(l3,...) — identical to R1
__device__ __forceinline__ void l3_consume(const f32x4 (&q)[4],
        int lp0, int lp1, int lp2, int lp3,
        unsigned long long hp0, unsigned long long hp1,
        unsigned long long hp2, unsigned long long hp3,
        float& v3, float& acc) {
    float inc3 = 0.f;
    #define GG(H, L) ((((H) >> ((L) & 63)) & 1ull) ? 1.0f : 0.0f)
    inc3 = fmaf(GG(hp0, lp0), q[0].x, inc3);
    inc3 = fmaf(GG(hp1, lp0), q[0].y, inc3);
    inc3 = fmaf(GG(hp2, lp0), q[0].z, inc3);
    inc3 = fmaf(GG(hp3, lp0), q[0].w, inc3);
    inc3 = fmaf(GG(hp0, lp1), q[1].x, inc3);
    inc3 = fmaf(GG(hp1, lp1), q[1].y, inc3);
    inc3 = fmaf(GG(hp2, lp1), q[1].z, inc3);
    inc3 = fmaf(GG(hp3, lp1), q[1].w, inc3);
    inc3 = fmaf(GG(hp0, lp2), q[2].x, inc3);
    inc3 = fmaf(GG(hp1, lp2), q[2].y, inc3);
    inc3 = fmaf(GG(hp2, lp2), q[2].z, inc3);
    inc3 = fmaf(GG(hp3, lp2), q[2].w, inc3);
    inc3 = fmaf(GG(hp0, lp3), q[3].x, inc3);
    inc3 = fmaf(GG(hp1, lp3), q[3].y, inc3);
    inc3 = fmaf(GG(hp2, lp3), q[3].z, inc3);
    inc3 = fmaf(GG(hp3, lp3), q[3].w, inc3);
    #undef GG
    float nn = v3 + inc3;
    bool ss = nn >= 1.0f;
    v3 = ss ? 0.f : nn;
    acc += ss ? 1.0f : 0.0f;
}

// ---------------- main: one wave per batch, 2-deep pipelined scan ----------------
__global__ __launch_bounds__(256, 1)
void snn_main(const float* __restrict__ x,
              const float* __restrict__ convw,
              const float* __restrict__ w1Tg,
              const float* __restrict__ w2Qg,
              float* __restrict__ out) {
    extern __shared__ float lds[];
    const int b = blockIdx.x;
    const int tid = threadIdx.x;

    {   // stage: w1T (+ zero row), w2Q, x
        const float4* s4 = (const float4*)w1Tg;
        float4* d4 = (float4*)lds;
        for (int i = tid; i < 8192; i += 256) d4[i] = s4[i];
        if (tid < 64) d4[8192 + tid] = make_float4(0.f, 0.f, 0.f, 0.f);
        const float4* s2 = (const float4*)w2Qg;
        float4* d2 = (float4*)(lds + W2B / 4);
        for (int i = tid; i < 1040; i += 256) d2[i] = s2[i];
        float* xL = lds + XB / 4;
        for (int i = tid; i < 2064; i += 256) {
            int l = i - 3;
            xL[i] = (l >= 0 && l < TN) ? x[b * TN + l] : 0.0f;
        }
    }
    __syncthreads();
    if (tid >= 64) return;
    const int lane = tid;

    const unsigned ldsbase = (unsigned)(uintptr_t)(void*)lds;
    const unsigned w1a = ldsbase + W1B + (unsigned)lane * 16u;          // + (c<<10)
    const unsigned w2a = ldsbase + W2B + (unsigned)(lane & 15) * 16u;   // + (l<<8)
    const unsigned xa  = ldsbase + XB;

    float cwa[7], cwb[7];
    #pragma unroll
    for (int k = 0; k < 7; ++k) {
        cwa[k] = convw[lane * 7 + k];
        cwb[k] = convw[(lane + 64) * 7 + k];
    }

    float v1a = 0.f, v1b = 0.f;
    float v20 = 0.f, v21 = 0.f, v22 = 0.f, v23 = 0.f;   // h = 4*lane + j
    float v3 = 0.f, acc = 0.f;

    float xw[12];
    {
        const float* xL = lds + XB / 4;
        float4 f0 = *(const float4*)(xL + 0);
        float4 f1 = *(const float4*)(xL + 4);
        float4 f2 = *(const float4*)(xL + 8);
        *(float4*)&xw[0] = f0; *(float4*)&xw[4] = f1; *(float4*)&xw[8] = f2;
    }

    f32x4 A[2][8];
    f32x4 Q[2][4];
    f32x4 fn;
    unsigned long long ovlo[2], ovhi[2];
    bool anyp = false;
    int lp0 = 64, lp1 = 64, lp2 = 64, lp3 = 64;
    unsigned long long hp0 = 0, hp1 = 0, hp2 = 0, hp3 = 0;

    // prologue: IF1 for t=0,1; issue a(0)->A[0], a(1)->A[1]
    {
        unsigned long long ma, mb;
        if1_step(xw, 0, cwa, cwb, v1a, v1b, ma, mb);
        issue_l2(ma, mb, w1a, A[0], ovlo[0], ovhi[0]);
        if1_step(xw, 1, cwa, cwb, v1a, v1b, ma, mb);
        issue_l2(ma, mb, w1a, A[1], ovlo[1], ovhi[1]);
    }

    #pragma unroll 1
    for (int tb = 0; tb < TN; tb += 4) {
        #pragma unroll 4
        for (int p = 0; p < 4; ++p) {
            const int pp = p & 1;

            // W1: drain a(t) + q(t-1) + xq; leave a(t+1) (8) in flight
            WAIT_LGKM(8);

            // deferred L3 for step t-1
            if (anyp) l3_consume(Q[pp ^ 1], lp0, lp1, lp2, lp3, hp0, hp1, hp2, hp3, v3, acc);
            anyp = false;

            // L2 consume (ascending c: 8 slots then rare overflow)
            f32x4 inc = A[pp][0];
            inc += A[pp][1]; inc += A[pp][2]; inc += A[pp][3];
            inc += A[pp][4]; inc += A[pp][5]; inc += A[pp][6]; inc += A[pp][7];
            {
                unsigned long long lo = ovlo[pp], hi = ovhi[pp];
                while (lo | hi) {
                    int c = pop_next(lo, hi);
                    f32x4 t4; ds_load4(t4, w1a + ((unsigned)c << 10));
                    WAIT_LGKM(0);
                    inc += t4;
                }
            }
            // IF layer 2
            float n0 = v20 + inc.x, n1 = v21 + inc.y, n2 = v22 + inc.z, n3 = v23 + inc.w;
            bool s0 = n0 >= 1.0f, s1 = n1 >= 1.0f, s2 = n2 >= 1.0f, s3 = n3 >= 1.0f;
            unsigned long long h0 = __ballot(s0), h1 = __ballot(s1);
            unsigned long long h2 = __ballot(s2), h3 = __ballot(s3);
            v20 = s0 ? 0.f : n0; v21 = s1 ? 0.f : n1;
            v22 = s2 ? 0.f : n2; v23 = s3 ? 0.f : n3;

            // layer-1 IF for t+2 (independent chain, runs 2 ahead)
            unsigned long long nma, nmb;
            if1_step(xw, p + 2, cwa, cwb, v1a, v1b, nma, nmb);

            // L3: issue q(t) (<=4 groups) or rare immediate exact path
            unsigned long long anym = h0 | h1 | h2 | h3;
            if (anym) {
                unsigned long long m = anym;
                int l0 = pop_one(m), l1 = pop_one(m), l2 = pop_one(m), l3 = pop_one(m);
                if (m == 0ull) {
                    ds_load4(Q[pp][0], w2a + ((unsigned)l0 << 8));
                    ds_load4(Q[pp][1], w2a + ((unsigned)l1 << 8));
                    ds_load4(Q[pp][2], w2a + ((unsigned)l2 << 8));
                    ds_load4(Q[pp][3], w2a + ((unsigned)l3 << 8));
                    lp0 = l0; lp1 = l1; lp2 = l2; lp3 = l3;
                    hp0 = h0; hp1 = h1; hp2 = h2; hp3 = h3;
                    anyp = true;
                } else {
                    float inc3 = 0.f;
                    unsigned long long mm = anym;
                    while (mm) {
                        int l = pop_one(mm);
                        f32x4 q; ds_load4(q, w2a + ((unsigned)l << 8));
                        WAIT_LGKM(0);
                        inc3 += ((h0 >> l) & 1ull) ? q.x : 0.0f;
                        inc3 += ((h1 >> l) & 1ull) ? q.y : 0.0f;
                        inc3 += ((h2 >> l) & 1ull) ? q.z : 0.0f;
                        inc3 += ((h3 >> l) & 1ull) ? q.w : 0.0f;
                    }
                    float nn = v3 + inc3;
                    bool ss = nn >= 1.0f;
                    v3 = ss ? 0.f : nn;
                    acc += ss ? 1.0f : 0.0f;
                }
            }

            // x prefetch for next block (issued between q and b for static counts)
            if (p == 0) ds_load4(fn, xa + (unsigned)(tb + 12) * 4u);

            // issue a(t+2) into the set just consumed
            issue_l2(nma, nmb, w1a, A[pp], ovlo[pp], ovhi[pp]);

            if (p == 3) {
                #pragma unroll
                for (int i = 0; i < 8; ++i) xw[i] = xw[i + 4];
                xw[8] = fn.x; xw[9] = fn.y; xw[10] = fn.z; xw[11] = fn.w;
            }
        }
    }

    // epilogue: finish deferred L3 for t = 2047 (was issued into Q[1])
    WAIT_LGKM(0);
    if (anyp) l3_consume(Q[1], lp0, lp1, lp2, lp3, hp0, hp1, hp2, hp3, v3, acc);

    if (lane < 10) out[b * 10 + lane] = acc * (1.0f / 2048.0f);
}

extern "C" void kernel_launch(void* const* d_in, const int* in_sizes, int n_in,
                              void* d_out, int out_size, void* d_ws, size_t ws_size,
                              hipStream_t stream) {
    const float* x     = (const float*)d_in[0];
    const float* convw = (const float*)d_in[1];
    const float* w1    = (const float*)d_in[2];
    const float* w2    = (const float*)d_in[3];
    float* w1T = (float*)d_ws;                 // 131072 B
    float* w2Q = (float*)d_ws + 32768;         //  16640 B

    prep_kernel<<<33, 256, 0, stream>>>(w1, w2, w1T, w2Q);

    const size_t ldsz = 156992;   // bytes
    (void)hipFuncSetAttribute(reinterpret_cast<const void*>(snn_main),
                              hipFuncAttributeMaxDynamicSharedMemorySize, (int)ldsz);
    snn_main<<<128, 256, ldsz, stream>>>(x, convw, w1T, w2Q, (float*)d_out);
}